// Round 2
// baseline (377.616 us; speedup 1.0000x reference)
//
#include <hip/hip_runtime.h>

// Problem constants (from reference)
#define BB 4
#define PP 12000
#define CC 64
#define HH 512
#define WW 512

// Kernel 1: winner[b*H*W + y*W + x] = max p among pillars hitting that cell.
// Winner buffer pre-initialized to -1 (0xFF memset). Max-p == last-write-wins
// in p order, matching XLA scatter-set semantics with duplicate indices.
__global__ void __launch_bounds__(256) winner_scatter(
    const int* __restrict__ coords, int* __restrict__ winner) {
    int tid = blockIdx.x * blockDim.x + threadIdx.x;
    if (tid >= BB * PP) return;
    int4 c4 = ((const int4*)coords)[tid];  // (batch, y, x, z)
    int y = c4.y;
    int x = c4.z;
    if (x >= 0 && x < WW && y >= 0 && y < HH) {
        int b = tid / PP;
        int p = tid - b * PP;
        atomicMax(&winner[(b * HH + y) * WW + x], p);
    }
}

// Kernel 2: output-linear fill, 8 cells (32 B) per thread.
// Thread gid owns float4s {2*gid, 2*gid+1} of out[B,C,H,W] -> stores form ONE
// sequential stream (memset-like). Per thread: 2 coalesced int4 winner reads
// (issued back-to-back for MLP), <=8 predicated gathers from the 12 MB feature
// table (LLC-resident), 2 nontemporal float4 stores (don't let 268 MB of
// dead-on-write output evict winner/features from L2).
typedef float f4_ev __attribute__((ext_vector_type(4)));

__global__ void __launch_bounds__(256) fill_linear8(
    const float* __restrict__ feat, const int4* __restrict__ winner4,
    float4* __restrict__ out4) {
    int gid = blockIdx.x * blockDim.x + threadIdx.x;  // 0 .. B*C*H*W/8 = 2^23
    // out float4 index = 2*gid; decode (b,c,y,x8) from gid:
    int x8 = gid & (WW / 8 - 1);          // 6 bits
    int y  = (gid >> 6) & (HH - 1);       // 9 bits
    int c  = (gid >> 15) & (CC - 1);      // 6 bits
    int b  = gid >> 21;                   // 2 bits

    int widx = (b * HH + y) * (WW / 4) + x8 * 2;
    int4 wa = winner4[widx];
    int4 wb = winner4[widx + 1];

    const float* fbase = feat + (size_t)b * (PP * CC) + c;
    float4 v0, v1;
    v0.x = (wa.x >= 0) ? fbase[(size_t)wa.x * CC] : 0.0f;
    v0.y = (wa.y >= 0) ? fbase[(size_t)wa.y * CC] : 0.0f;
    v0.z = (wa.z >= 0) ? fbase[(size_t)wa.z * CC] : 0.0f;
    v0.w = (wa.w >= 0) ? fbase[(size_t)wa.w * CC] : 0.0f;
    v1.x = (wb.x >= 0) ? fbase[(size_t)wb.x * CC] : 0.0f;
    v1.y = (wb.y >= 0) ? fbase[(size_t)wb.y * CC] : 0.0f;
    v1.z = (wb.z >= 0) ? fbase[(size_t)wb.z * CC] : 0.0f;
    v1.w = (wb.w >= 0) ? fbase[(size_t)wb.w * CC] : 0.0f;

    size_t o = (size_t)gid * 2;
    __builtin_nontemporal_store(*(const f4_ev*)&v0, (f4_ev*)&out4[o]);
    __builtin_nontemporal_store(*(const f4_ev*)&v1, (f4_ev*)&out4[o + 1]);
}

extern "C" void kernel_launch(void* const* d_in, const int* in_sizes, int n_in,
                              void* d_out, int out_size, void* d_ws, size_t ws_size,
                              hipStream_t stream) {
    const float* feat   = (const float*)d_in[0];  // [B, P, C] fp32
    const int*   coords = (const int*)d_in[1];    // [B, P, 4] int32
    float* out = (float*)d_out;                   // [B, C, H, W] fp32
    int* winner = (int*)d_ws;                     // [B, H, W] int32 (4 MB)

    // Init winner map to -1 (0xFF bytes). d_ws is poisoned each call, so this
    // must run every launch. Graph-capture-safe (memset node).
    hipMemsetAsync(winner, 0xFF, (size_t)BB * HH * WW * sizeof(int), stream);

    // Resolve duplicates: winner = max pillar index per cell.
    {
        int n = BB * PP;
        winner_scatter<<<(n + 255) / 256, 256, 0, stream>>>(coords, winner);
    }

    // Output-linear fill: zeros + gathered features, one sequential store
    // stream, 32 B per thread.
    {
        int n = BB * CC * HH * WW / 8;  // 8,388,608 threads
        fill_linear8<<<n / 256, 256, 0, stream>>>(
            feat, (const int4*)winner, (float4*)out);
    }
}

// Round 3
// 279.097 us; speedup vs baseline: 1.3530x; 1.3530x over previous
//
#include <hip/hip_runtime.h>

// Problem constants (from reference)
#define BB 4
#define PP 12000
#define CC 64
#define HH 512
#define WW 512

// Kernel 1: winner[b*H*W + y*W + x] = max p among pillars hitting that cell.
// Winner buffer pre-initialized to -1 (0xFF memset). Max-p == last-write-wins
// in p order, matching XLA scatter-set semantics with duplicate indices.
__global__ void __launch_bounds__(256) winner_scatter(
    const int* __restrict__ coords, int* __restrict__ winner) {
    int tid = blockIdx.x * blockDim.x + threadIdx.x;
    if (tid >= BB * PP) return;
    int4 c4 = ((const int4*)coords)[tid];  // (batch, y, x, z)
    int y = c4.y;
    int x = c4.z;
    if (x >= 0 && x < WW && y >= 0 && y < HH) {
        int b = tid / PP;
        int p = tid - b * PP;
        atomicMax(&winner[(b * HH + y) * WW + x], p);
    }
}

// Kernel 2: output-linear fill, 4 channels x 4 cells (64 B of out) per thread.
// Lanes sweep consecutive x4, so EVERY load/store instruction is a fully
// coalesced 1 KB/wave access (round-2 lesson: per-instruction coalescing of
// the store stream is worth ~100 us; never stride the lane mapping).
// Per thread: 1 int4 winner read (amortized over 4 channels -> winner traffic
// /4 vs round-1), <=4 float4 gathers from feat (channels contiguous), 4x4
// in-register transpose, 4 nontemporal float4 stores (keep the 268 MB
// dead-on-write output from evicting winner/feat from L2).
typedef float f4_ev __attribute__((ext_vector_type(4)));

__global__ void __launch_bounds__(256) fill_c4(
    const float4* __restrict__ feat4, const int4* __restrict__ winner4,
    float4* __restrict__ out4) {
    int gid = blockIdx.x * blockDim.x + threadIdx.x;  // 0 .. B*(C/4)*H*(W/4) = 2^22
    int x4 = gid & (WW / 4 - 1);          // 7 bits
    int y  = (gid >> 7) & (HH - 1);       // 9 bits
    int c4 = (gid >> 16) & (CC / 4 - 1);  // 4 bits
    int b  = gid >> 20;                   // 2 bits

    int4 w4 = winner4[(b * HH + y) * (WW / 4) + x4];

    // feat as float4 rows: [B, P, C/4]; this thread reads channel block c4.
    const float4* fb = feat4 + (size_t)b * (PP * (CC / 4)) + c4;
    float4 z = {0.f, 0.f, 0.f, 0.f};
    float4 f0 = z, f1 = z, f2 = z, f3 = z;
    if (w4.x >= 0) f0 = fb[(size_t)w4.x * (CC / 4)];
    if (w4.y >= 0) f1 = fb[(size_t)w4.y * (CC / 4)];
    if (w4.z >= 0) f2 = fb[(size_t)w4.z * (CC / 4)];
    if (w4.w >= 0) f3 = fb[(size_t)w4.w * (CC / 4)];

    // Transpose: store for channel c4*4+j packs component j of the 4 cells.
    size_t o = ((size_t)(b * CC + c4 * 4) * HH + y) * (WW / 4) + x4;
    const size_t cstride = (size_t)HH * (WW / 4);  // one channel plane of float4s
    float4 s0 = {f0.x, f1.x, f2.x, f3.x};
    float4 s1 = {f0.y, f1.y, f2.y, f3.y};
    float4 s2 = {f0.z, f1.z, f2.z, f3.z};
    float4 s3 = {f0.w, f1.w, f2.w, f3.w};
    __builtin_nontemporal_store(*(const f4_ev*)&s0, (f4_ev*)&out4[o]);
    __builtin_nontemporal_store(*(const f4_ev*)&s1, (f4_ev*)&out4[o + cstride]);
    __builtin_nontemporal_store(*(const f4_ev*)&s2, (f4_ev*)&out4[o + 2 * cstride]);
    __builtin_nontemporal_store(*(const f4_ev*)&s3, (f4_ev*)&out4[o + 3 * cstride]);
}

extern "C" void kernel_launch(void* const* d_in, const int* in_sizes, int n_in,
                              void* d_out, int out_size, void* d_ws, size_t ws_size,
                              hipStream_t stream) {
    const float* feat   = (const float*)d_in[0];  // [B, P, C] fp32
    const int*   coords = (const int*)d_in[1];    // [B, P, 4] int32
    float* out = (float*)d_out;                   // [B, C, H, W] fp32
    int* winner = (int*)d_ws;                     // [B, H, W] int32 (4 MB)

    // Init winner map to -1 (0xFF bytes). d_ws is poisoned each call, so this
    // must run every launch. Graph-capture-safe (memset node).
    hipMemsetAsync(winner, 0xFF, (size_t)BB * HH * WW * sizeof(int), stream);

    // Resolve duplicates: winner = max pillar index per cell.
    {
        int n = BB * PP;
        winner_scatter<<<(n + 255) / 256, 256, 0, stream>>>(coords, winner);
    }

    // Output fill: 64 B of out per thread, all accesses wave-coalesced.
    {
        int n = BB * (CC / 4) * HH * (WW / 4);  // 4,194,304 threads
        fill_c4<<<n / 256, 256, 0, stream>>>(
            (const float4*)feat, (const int4*)winner, (float4*)out);
    }
}